// Round 3
// baseline (132.074 us; speedup 1.0000x reference)
//
#include <hip/hip_runtime.h>
#include <math.h>

// Problem constants (from reference):
//   vol: (B=1, C=1, W=96, H=96, D=64) float32, row-major -> vol[(x*96+y)*64+z]
//   out: (B,C,U=96,A=90,V=64) float32 -> out[(u*90+a)*64+v]
//   k[v] = v identically (V=D=64, SV=SD=1), so depth slice index == lane.
namespace {
constexpr int An = 90, Un = 96, Vn = 64, Wn = 96, Hn = 96, Dn = 64;
constexpr int NRAY = An * Un;       // 8640 (divisible by 64 -> 135 tiles)
constexpr int NSTEPS = Hn + Wn + 2; // 194
constexpr int NTILE = NRAY / 64;    // 135
}

// ---------------------------------------------------------------------------
// Phase 1: one lane per ray. Valid steps are a PREFIX of the step index
// (valid is sticky-false), so entry n == step. Entries stored TILED:
//   ents[(rayblk*NSTEPS + step)*64 + lane]  -> each step's wave store is one
// contiguous 512B transaction (fully coalesced), fixing R2's 42.9us
// uncoalesced-store bottleneck (was 64 cache lines per store instruction).
// Entry packed as float2: .x = __int_as_float(element offset), .y = weight.
// ---------------------------------------------------------------------------
__global__ __launch_bounds__(64)
void trace_kernel(float2* __restrict__ ents, int* __restrict__ counts)
{
    const int lane   = threadIdx.x;
    const int rayblk = blockIdx.x;          // 0..134
    const int ray    = rayblk * 64 + lane;  // a*96 + u
    const int a = ray / Un;
    const int u = ray - a * Un;

    const float EPSf = 1e-12f;
    const float INF  = __builtin_inff();
    const float DIAG = 1.41421356237309514547f;

    const float ang = (float)a * (float)(3.14159265358979323846 / 90.0);
    const float dx = (float)cos((double)ang);
    const float dy = (float)sin((double)ang);
    const float uu = (float)u - 47.5f;
    const float x0 = __fmul_rn(-uu, dy);
    const float y0 = __fmul_rn( uu, dx);

    const float xmin = -47.5f, xmax = 47.5f;
    const float ymin = -47.5f, ymax = 47.5f;

    float tx0, tx1;
    {
        const bool par = fabsf(dx) < EPSf;
        const float safe = par ? 1.0f : dx;
        const float t0 = __fdiv_rn(xmin - x0, safe);
        const float t1 = __fdiv_rn(xmax - x0, safe);
        const float lo = fminf(t0, t1), hi = fmaxf(t0, t1);
        const bool inside = (x0 >= xmin) && (x0 <= xmax);
        tx0 = par ? (inside ? -INF : INF) : lo;
        tx1 = par ? (inside ?  INF : -INF) : hi;
    }
    float ty0, ty1;
    {
        const bool par = fabsf(dy) < EPSf;
        const float safe = par ? 1.0f : dy;
        const float t0 = __fdiv_rn(ymin - y0, safe);
        const float t1 = __fdiv_rn(ymax - y0, safe);
        const float lo = fminf(t0, t1), hi = fmaxf(t0, t1);
        const bool inside = (y0 >= ymin) && (y0 <= ymax);
        ty0 = par ? (inside ? -INF : INF) : lo;
        ty1 = par ? (inside ?  INF : -INF) : hi;
    }

    const float t_entry = fmaxf(tx0, ty0);
    const float t_exit  = fminf(tx1, ty1);
    bool  alive = t_entry < t_exit;
    const float te  = alive ? t_entry : 0.0f;
    const float tex = alive ? t_exit  : 0.0f;

    float x = __fadd_rn(x0, __fmul_rn(te, dx));
    float y = __fadd_rn(y0, __fmul_rn(te, dy));
    int i = (int)fminf(fmaxf(rintf(__fadd_rn(x, 47.5f)), 0.0f), 95.0f);
    int j = (int)fminf(fmaxf(rintf(__fadd_rn(y, 47.5f)), 0.0f), 95.0f);
    float t = te;

    const bool okx = fabsf(dx) > EPSf;
    const bool oky = fabsf(dy) > EPSf;
    // reciprocal-mul instead of per-step IEEE div: <=2 ulp vs reference; only
    // matters at exact corner ties whose segments are ~zero-length.
    const float inv_dx = okx ? __fdiv_rn(1.0f, dx) : 0.0f;
    const float inv_dy = oky ? __fdiv_rn(1.0f, dy) : 0.0f;
    const float wscale = __fdiv_rn(DIAG, fmaxf(fabsf(dx) + fabsf(dy), EPSf));
    const float tex_m_eps = __fadd_rn(tex, -EPSf);

    float2* __restrict__ base = ents + (size_t)rayblk * NSTEPS * 64 + lane;
    int n = 0;

    for (int step = 0; step < NSTEPS; ++step) {
        const bool valid = alive && (t < tex_m_eps);
        if (!__ballot(valid)) break;   // all rays in this tile done
        if (valid) {
            const float fi = (float)i, fj = (float)j;
            const float xn = (dx > 0.0f) ? (fi + 0.5f) - 47.5f
                           : (dx < 0.0f) ? (fi - 0.5f) - 47.5f : INF;
            const float yn = (dy > 0.0f) ? (fj + 0.5f) - 47.5f
                           : (dy < 0.0f) ? (fj - 0.5f) - 47.5f : INF;
            const float txc = okx ? __fmul_rn(xn - x, inv_dx) : INF;
            const float tyc = oky ? __fmul_rn(yn - y, inv_dy) : INF;
            const float dt  = fminf(fminf(txc, tyc), __fadd_rn(tex, -t));
            const float seg = fmaxf(0.0f, __fmul_rn(dt, wscale));

            float2 e;
            e.x = __int_as_float((i * Hn + j) * Dn);  // element offset into vol
            e.y = seg;
            base[step * 64] = e;      // coalesced: 64 lanes -> 512B contiguous
            ++n;

            const int i_n = i + ((txc <= tyc) ? ((dx > 0.0f) ? 1 : -1) : 0);
            const int j_n = j + ((tyc <= txc) ? ((dy > 0.0f) ? 1 : -1) : 0);
            const bool inb = (i_n >= 0) && (i_n < Wn) && (j_n >= 0) && (j_n < Hn);
            x = __fadd_rn(x, __fmul_rn(dx, dt));
            y = __fadd_rn(y, __fmul_rn(dy, dt));
            t = __fadd_rn(t, dt);
            i = i_n; j = j_n;
            alive = inb;
        }
    }
    counts[ray] = n;
}

// ---------------------------------------------------------------------------
// Phase 2: one wave per ray (lane = v, contiguous depth axis), 4 rays/block.
// Entry n for ray r lives at ents[(rayblk*NSTEPS + n)*64 + (r&63)]:
// wave-uniform 8B broadcast load; consecutive rays share 64B lines.
// 4 independent accumulator chains for ILP over the 2-deep load chain.
// ---------------------------------------------------------------------------
__global__ __launch_bounds__(256)
void gather_kernel(const float* __restrict__ vol,
                   const float2* __restrict__ ents,
                   const int* __restrict__ counts,
                   float* __restrict__ out)
{
    const int wid = threadIdx.x >> 6;                 // wave in block 0..3
    const int ray = (blockIdx.x << 2) + wid;          // a*96 + u
    const int v   = threadIdx.x & 63;

    const int rayblk = ray >> 6;
    const int rl     = ray & 63;
    const int cnt = counts[ray];
    const float2* __restrict__ e = ents + ((size_t)rayblk * NSTEPS) * 64 + rl;
    const float* __restrict__ volv = vol + v;

    float a0 = 0.0f, a1 = 0.0f, a2 = 0.0f, a3 = 0.0f;
    int n = 0;
    for (; n + 4 <= cnt; n += 4) {
        const float2 e0 = e[(n + 0) * 64];
        const float2 e1 = e[(n + 1) * 64];
        const float2 e2 = e[(n + 2) * 64];
        const float2 e3 = e[(n + 3) * 64];
        a0 = fmaf(e0.y, volv[__float_as_int(e0.x)], a0);
        a1 = fmaf(e1.y, volv[__float_as_int(e1.x)], a1);
        a2 = fmaf(e2.y, volv[__float_as_int(e2.x)], a2);
        a3 = fmaf(e3.y, volv[__float_as_int(e3.x)], a3);
    }
    float acc = (a0 + a1) + (a2 + a3);
    for (; n < cnt; ++n) {
        const float2 e0 = e[n * 64];
        acc = fmaf(e0.y, volv[__float_as_int(e0.x)], acc);
    }

    const int a = ray / Un;
    const int u = ray - a * Un;
    out[(u * An + a) * Vn + v] = acc;
}

// ---------------------------------------------------------------------------
// Fallback: the proven single-kernel version (used if ws_size is too small).
// ---------------------------------------------------------------------------
__global__ __launch_bounds__(64)
void siddon_fwd_kernel(const float* __restrict__ vol, float* __restrict__ out)
{
    const int ray = blockIdx.x;
    const int a   = ray / Un;
    const int u   = ray - a * Un;
    const int v   = threadIdx.x;

    const float EPSf = 1e-12f;
    const float INF  = __builtin_inff();
    const float DIAG = 1.41421356237309514547f;

    const float ang = (float)a * (float)(3.14159265358979323846 / 90.0);
    const float dx = (float)cos((double)ang);
    const float dy = (float)sin((double)ang);
    const float uu = (float)u - 47.5f;
    const float x0 = __fmul_rn(-uu, dy);
    const float y0 = __fmul_rn( uu, dx);

    const float xmin = -47.5f, xmax = 47.5f;
    const float ymin = -47.5f, ymax = 47.5f;

    float tx0, tx1;
    {
        const bool par = fabsf(dx) < EPSf;
        const float safe = par ? 1.0f : dx;
        const float t0 = __fdiv_rn(xmin - x0, safe);
        const float t1 = __fdiv_rn(xmax - x0, safe);
        const float lo = fminf(t0, t1), hi = fmaxf(t0, t1);
        const bool inside = (x0 >= xmin) && (x0 <= xmax);
        tx0 = par ? (inside ? -INF : INF) : lo;
        tx1 = par ? (inside ?  INF : -INF) : hi;
    }
    float ty0, ty1;
    {
        const bool par = fabsf(dy) < EPSf;
        const float safe = par ? 1.0f : dy;
        const float t0 = __fdiv_rn(ymin - y0, safe);
        const float t1 = __fdiv_rn(ymax - y0, safe);
        const float lo = fminf(t0, t1), hi = fmaxf(t0, t1);
        const bool inside = (y0 >= ymin) && (y0 <= ymax);
        ty0 = par ? (inside ? -INF : INF) : lo;
        ty1 = par ? (inside ?  INF : -INF) : hi;
    }

    const float t_entry = fmaxf(tx0, ty0);
    const float t_exit  = fminf(tx1, ty1);
    bool  alive = t_entry < t_exit;
    const float te  = alive ? t_entry : 0.0f;
    const float tex = alive ? t_exit  : 0.0f;

    float x = __fadd_rn(x0, __fmul_rn(te, dx));
    float y = __fadd_rn(y0, __fmul_rn(te, dy));
    int i = (int)fminf(fmaxf(rintf(__fadd_rn(x, 47.5f)), 0.0f), 95.0f);
    int j = (int)fminf(fmaxf(rintf(__fadd_rn(y, 47.5f)), 0.0f), 95.0f);
    float t = te;

    const float inv_sum = fmaxf(fabsf(dx) + fabsf(dy), EPSf);

    float acc = 0.0f;
    const float* __restrict__ volv = vol + v;

    for (int n = 0; n < NSTEPS; ++n) {
        const bool valid = alive && (t < __fadd_rn(tex, -EPSf));
        if (!valid) break;

        const float fi = (float)i, fj = (float)j;
        const float xn = (dx > 0.0f) ? (fi + 0.5f) - 47.5f
                       : (dx < 0.0f) ? (fi - 0.5f) - 47.5f : INF;
        const float yn = (dy > 0.0f) ? (fj + 0.5f) - 47.5f
                       : (dy < 0.0f) ? (fj - 0.5f) - 47.5f : INF;
        const float txc = (fabsf(dx) > EPSf) ? __fdiv_rn(xn - x, dx) : INF;
        const float tyc = (fabsf(dy) > EPSf) ? __fdiv_rn(yn - y, dy) : INF;
        const float dt  = fminf(fminf(txc, tyc), __fadd_rn(tex, -t));
        const float seg = fmaxf(0.0f, __fdiv_rn(__fmul_rn(dt, DIAG), inv_sum));

        acc = fmaf(seg, volv[(i * Hn + j) * Dn], acc);

        const int i_n = i + ((txc <= tyc) ? ((dx > 0.0f) ? 1 : -1) : 0);
        const int j_n = j + ((tyc <= txc) ? ((dy > 0.0f) ? 1 : -1) : 0);
        const bool inb = (i_n >= 0) && (i_n < Wn) && (j_n >= 0) && (j_n < Hn);
        x = __fadd_rn(x, __fmul_rn(dx, dt));
        y = __fadd_rn(y, __fmul_rn(dy, dt));
        t = __fadd_rn(t, dt);
        i = i_n; j = j_n;
        alive = inb;
    }

    out[(u * An + a) * Vn + v] = acc;
}

extern "C" void kernel_launch(void* const* d_in, const int* in_sizes, int n_in,
                              void* d_out, int out_size, void* d_ws, size_t ws_size,
                              hipStream_t stream) {
    const float* vol = (const float*)d_in[0];
    float* out = (float*)d_out;

    const size_t ents_bytes   = (size_t)NTILE * NSTEPS * 64 * sizeof(float2); // 13.4 MB
    const size_t counts_bytes = (size_t)NRAY * sizeof(int);
    if (ws_size >= ents_bytes + counts_bytes) {
        float2* ents   = (float2*)d_ws;
        int*    counts = (int*)((char*)d_ws + ents_bytes);
        hipLaunchKernelGGL(trace_kernel, dim3(NTILE), dim3(64), 0, stream,
                           ents, counts);
        hipLaunchKernelGGL(gather_kernel, dim3(NRAY / 4), dim3(256), 0, stream,
                           vol, ents, counts, out);
    } else {
        hipLaunchKernelGGL(siddon_fwd_kernel, dim3(NRAY), dim3(64), 0, stream,
                           vol, out);
    }
}

// Round 4
// 95.870 us; speedup vs baseline: 1.3776x; 1.3776x over previous
//
#include <hip/hip_runtime.h>
#include <math.h>

// Problem constants (from reference):
//   vol: (B=1, C=1, W=96, H=96, D=64) float32, row-major -> vol[(x*96+y)*64+z]
//   out: (B,C,U=96,A=90,V=64) float32 -> out[(u*90+a)*64+v]
//   k[v] = v identically (V=D=64, SV=SD=1), so depth slice index == lane.
namespace {
constexpr int An = 90, Un = 96, Vn = 64, Wn = 96, Hn = 96, Dn = 64;
constexpr int NRAY   = An * Un;        // 8640
constexpr int NSTEPS = Hn + Wn + 2;    // 194
constexpr int NSP    = NSTEPS + 1;     // 195: LDS row pad -> bank stride 390%32=6,
                                       // gcd(6,32)=2 -> 2-way conflict = free (m136)
constexpr int TILE   = 32;             // rays per block (96%32==0: tile never spans angles)
constexpr int NTILES = NRAY / TILE;    // 270 blocks (~1.05/CU, 3 resident by LDS)
constexpr int RPW    = 4;              // rays gathered per wave (8 waves * 4 = 32)
}

// Fused Siddon projector:
//   Phase 1 (wave 0, lanes 0..31): trace 32 rays -> LDS entry lists.
//     LDS ds_write WAR stalls are ~30 cyc (vs ~400 cyc exposed global-store
//     WAR waits that made the standalone trace kernel ~43 us at 1 wave/CU).
//   Phase 2 (8 waves, lane = v): per step ds_read (uniform addr = broadcast,
//     conflict-free) + coalesced 256B vol row load + fma, unrolled x8 so 8
//     vol loads are in flight (hides ~200 cyc L2 latency).
// Entries never touch global memory: removes R3's 13.4 MB HBM round trip
// that made gather an HBM-latency-bound pointer walk (47.9 us, VALUBusy 15%).
__global__ __launch_bounds__(512)
void siddon_fused(const float* __restrict__ vol, float* __restrict__ out)
{
    __shared__ float2 sE[TILE][NSP];   // .x = __int_as_float(vol element offset), .y = weight
    __shared__ int    sCnt[TILE];

    const int tid  = threadIdx.x;
    const int tile = blockIdx.x;

    // ---------------- Phase 1: trace (wave 0 only) ----------------
    if (tid < 64) {
        const int  rl     = tid;
        const bool tracer = rl < TILE;           // lanes 32..63 ride along dead
        const int  ray    = tile * TILE + (tracer ? rl : 0);
        const int  a = ray / Un;
        const int  u = ray - a * Un;

        const float EPSf = 1e-12f;
        const float INF  = __builtin_inff();
        const float DIAG = 1.41421356237309514547f;

        const float ang = (float)a * (float)(3.14159265358979323846 / 90.0);
        const float dx = (float)cos((double)ang);
        const float dy = (float)sin((double)ang);
        const float uu = (float)u - 47.5f;
        const float x0 = __fmul_rn(-uu, dy);
        const float y0 = __fmul_rn( uu, dx);

        const float xmin = -47.5f, xmax = 47.5f;
        const float ymin = -47.5f, ymax = 47.5f;

        float tx0, tx1;
        {
            const bool par = fabsf(dx) < EPSf;
            const float safe = par ? 1.0f : dx;
            const float t0 = __fdiv_rn(xmin - x0, safe);
            const float t1 = __fdiv_rn(xmax - x0, safe);
            const float lo = fminf(t0, t1), hi = fmaxf(t0, t1);
            const bool inside = (x0 >= xmin) && (x0 <= xmax);
            tx0 = par ? (inside ? -INF : INF) : lo;
            tx1 = par ? (inside ?  INF : -INF) : hi;
        }
        float ty0, ty1;
        {
            const bool par = fabsf(dy) < EPSf;
            const float safe = par ? 1.0f : dy;
            const float t0 = __fdiv_rn(ymin - y0, safe);
            const float t1 = __fdiv_rn(ymax - y0, safe);
            const float lo = fminf(t0, t1), hi = fmaxf(t0, t1);
            const bool inside = (y0 >= ymin) && (y0 <= ymax);
            ty0 = par ? (inside ? -INF : INF) : lo;
            ty1 = par ? (inside ?  INF : -INF) : hi;
        }

        const float t_entry = fmaxf(tx0, ty0);
        const float t_exit  = fminf(tx1, ty1);
        bool  alive = tracer && (t_entry < t_exit);
        const float te  = (t_entry < t_exit) ? t_entry : 0.0f;
        const float tex = (t_entry < t_exit) ? t_exit  : 0.0f;

        float x = __fadd_rn(x0, __fmul_rn(te, dx));
        float y = __fadd_rn(y0, __fmul_rn(te, dy));
        int i = (int)fminf(fmaxf(rintf(__fadd_rn(x, 47.5f)), 0.0f), 95.0f);
        int j = (int)fminf(fmaxf(rintf(__fadd_rn(y, 47.5f)), 0.0f), 95.0f);
        float t = te;

        const bool okx = fabsf(dx) > EPSf;
        const bool oky = fabsf(dy) > EPSf;
        // reciprocal-mul instead of per-step IEEE div: <=2 ulp vs reference
        // (validated R2/R3: absmax stayed 0.25 vs 1.18 threshold).
        const float inv_dx = okx ? __fdiv_rn(1.0f, dx) : 0.0f;
        const float inv_dy = oky ? __fdiv_rn(1.0f, dy) : 0.0f;
        const float wscale = __fdiv_rn(DIAG, fmaxf(fabsf(dx) + fabsf(dy), EPSf));
        const float tex_m_eps = __fadd_rn(tex, -EPSf);
        // xn = (fi±0.5)-47.5 == fi + cx exactly (all multiples of 0.5, |.|<144)
        const float cx = (dx > 0.0f) ? -47.0f : -48.0f;
        const float cy = (dy > 0.0f) ? -47.0f : -48.0f;
        const int   si = (dx > 0.0f) ? 1 : -1;   // dx==0 -> never selected
        const int   sj = (dy > 0.0f) ? 1 : -1;   // dy==0 -> never selected

        int n = 0;
        for (int step = 0; step < NSTEPS; ++step) {
            const bool valid = alive && (t < tex_m_eps);
            if (!__ballot(valid)) break;   // all 32 rays of the tile done
            if (valid) {
                const float txc = okx ? __fmul_rn(((float)i + cx) - x, inv_dx) : INF;
                const float tyc = oky ? __fmul_rn(((float)j + cy) - y, inv_dy) : INF;
                const float dt  = fminf(fminf(txc, tyc), __fadd_rn(tex, -t));
                const float seg = fmaxf(0.0f, __fmul_rn(dt, wscale));

                float2 e;
                e.x = __int_as_float((i * Hn + j) * Dn);
                e.y = seg;
                sE[rl][n] = e;
                ++n;

                const int i_n = i + ((txc <= tyc) ? si : 0);
                const int j_n = j + ((tyc <= txc) ? sj : 0);
                const bool inb = (i_n >= 0) && (i_n < Wn) && (j_n >= 0) && (j_n < Hn);
                x = __fadd_rn(x, __fmul_rn(dx, dt));
                y = __fadd_rn(y, __fmul_rn(dy, dt));
                t = __fadd_rn(t, dt);
                i = i_n; j = j_n;
                alive = inb;
            }
        }
        if (tracer) sCnt[rl] = n;
    }
    __syncthreads();

    // ---------------- Phase 2: gather (all 8 waves, lane = v) ----------------
    const int wid = tid >> 6;          // 0..7
    const int v   = tid & 63;
    const float* __restrict__ volv = vol + v;

    for (int k = 0; k < RPW; ++k) {
        const int rl  = wid * RPW + k;
        const int ray = tile * TILE + rl;
        const int cnt = sCnt[rl];
        const float2* e = &sE[rl][0];

        float a0 = 0.0f, a1 = 0.0f, a2 = 0.0f, a3 = 0.0f;
        int n = 0;
        for (; n + 8 <= cnt; n += 8) {
            const float2 e0 = e[n + 0], e1 = e[n + 1], e2 = e[n + 2], e3 = e[n + 3];
            const float2 e4 = e[n + 4], e5 = e[n + 5], e6 = e[n + 6], e7 = e[n + 7];
            const float v0 = volv[__float_as_int(e0.x)];
            const float v1 = volv[__float_as_int(e1.x)];
            const float v2 = volv[__float_as_int(e2.x)];
            const float v3 = volv[__float_as_int(e3.x)];
            const float v4 = volv[__float_as_int(e4.x)];
            const float v5 = volv[__float_as_int(e5.x)];
            const float v6 = volv[__float_as_int(e6.x)];
            const float v7 = volv[__float_as_int(e7.x)];
            a0 = fmaf(e0.y, v0, a0);
            a1 = fmaf(e1.y, v1, a1);
            a2 = fmaf(e2.y, v2, a2);
            a3 = fmaf(e3.y, v3, a3);
            a0 = fmaf(e4.y, v4, a0);
            a1 = fmaf(e5.y, v5, a1);
            a2 = fmaf(e6.y, v6, a2);
            a3 = fmaf(e7.y, v7, a3);
        }
        float acc = (a0 + a1) + (a2 + a3);
        for (; n < cnt; ++n) {
            const float2 e0 = e[n];
            acc = fmaf(e0.y, volv[__float_as_int(e0.x)], acc);
        }

        const int a = ray / Un;
        const int u = ray - a * Un;
        out[(u * An + a) * Vn + v] = acc;
    }
}

extern "C" void kernel_launch(void* const* d_in, const int* in_sizes, int n_in,
                              void* d_out, int out_size, void* d_ws, size_t ws_size,
                              hipStream_t stream) {
    const float* vol = (const float*)d_in[0];
    float* out = (float*)d_out;
    hipLaunchKernelGGL(siddon_fused, dim3(NTILES), dim3(512), 0, stream, vol, out);
}

// Round 5
// 94.336 us; speedup vs baseline: 1.4000x; 1.0163x over previous
//
#include <hip/hip_runtime.h>
#include <math.h>

// Problem constants (from reference):
//   vol: (B=1, C=1, W=96, H=96, D=64) float32, row-major -> vol[(x*96+y)*64+z]
//   out: (B,C,U=96,A=90,V=64) float32 -> out[(u*90+a)*64+v]
//   k[v] = v identically (V=D=64, SV=SD=1), so depth slice index == lane.
namespace {
constexpr int An = 90, Un = 96, Vn = 64, Wn = 96, Hn = 96, Dn = 64;
constexpr int NRAY   = An * Un;        // 8640
constexpr int NSTEPS = Hn + Wn + 2;    // 194
constexpr int NSP    = 196;            // LDS row: 194 steps + pad to even ->
                                       // rows 16B-aligned (1568B = 98*16); bank
                                       // stride 392B = 98 dwords, 98%32=2 ->
                                       // 2-way conflict = free (m136)
constexpr int TILE   = 8;              // rays per block = waves per block
constexpr int NTILES = NRAY / TILE;    // 1080 blocks -> 4.2/CU (fixes R4's
                                       // 270-block grid = 15% occupancy)
}

// Fused Siddon projector, occupancy-first shape:
//   Phase 1 (wave 0, lanes 0..7): trace 8 rays -> LDS entry lists, padded to
//     a multiple of 8 with zero-weight entries (no gather tail loop).
//   Phase 2 (8 waves, lane = v): wave w gathers ray w. Per 8-entry batch:
//     4x ds_read_b128 (2 entries each, uniform addr = broadcast) + 8 coalesced
//     256B vol loads in flight + 8 fma into 4 accumulator chains.
// R4 post-mortem: 47.6us at 15% occupancy (270 blocks, 8 waves/CU) was
// L3/HBM-latency-bound (graph replay rewrites vol each iter -> first-touch
// misses) with nothing resident to hide it. 1080 blocks * 8 waves at
// 12.6KB LDS -> 32 waves/CU resident.
__global__ __launch_bounds__(512, 8)
void siddon_fused(const float* __restrict__ vol, float* __restrict__ out)
{
    __shared__ float2 sE[TILE][NSP];   // .x = __int_as_float(BYTE offset into vol), .y = weight
    __shared__ int    sCnt8[TILE];     // entry count rounded up to multiple of 8

    const int tid  = threadIdx.x;
    const int tile = blockIdx.x;

    // ---------------- Phase 1: trace (wave 0, lanes 0..TILE-1) ----------------
    if (tid < 64) {
        const int  rl     = tid;
        const bool tracer = rl < TILE;            // lanes 8..63 ride along dead
        const int  ray    = tile * TILE + (tracer ? rl : 0);
        const int  a = ray / Un;
        const int  u = ray - a * Un;

        const float EPSf = 1e-12f;
        const float INF  = __builtin_inff();
        const float DIAG = 1.41421356237309514547f;

        const float ang = (float)a * (float)(3.14159265358979323846 / 90.0);
        const float dx = (float)cos((double)ang);
        const float dy = (float)sin((double)ang);
        const float uu = (float)u - 47.5f;
        const float x0 = __fmul_rn(-uu, dy);
        const float y0 = __fmul_rn( uu, dx);

        const float xmin = -47.5f, xmax = 47.5f;
        const float ymin = -47.5f, ymax = 47.5f;

        float tx0, tx1;
        {
            const bool par = fabsf(dx) < EPSf;
            const float safe = par ? 1.0f : dx;
            const float t0 = __fdiv_rn(xmin - x0, safe);
            const float t1 = __fdiv_rn(xmax - x0, safe);
            const float lo = fminf(t0, t1), hi = fmaxf(t0, t1);
            const bool inside = (x0 >= xmin) && (x0 <= xmax);
            tx0 = par ? (inside ? -INF : INF) : lo;
            tx1 = par ? (inside ?  INF : -INF) : hi;
        }
        float ty0, ty1;
        {
            const bool par = fabsf(dy) < EPSf;
            const float safe = par ? 1.0f : dy;
            const float t0 = __fdiv_rn(ymin - y0, safe);
            const float t1 = __fdiv_rn(ymax - y0, safe);
            const float lo = fminf(t0, t1), hi = fmaxf(t0, t1);
            const bool inside = (y0 >= ymin) && (y0 <= ymax);
            ty0 = par ? (inside ? -INF : INF) : lo;
            ty1 = par ? (inside ?  INF : -INF) : hi;
        }

        const float t_entry = fmaxf(tx0, ty0);
        const float t_exit  = fminf(tx1, ty1);
        bool  alive = tracer && (t_entry < t_exit);
        const float te  = (t_entry < t_exit) ? t_entry : 0.0f;
        const float tex = (t_entry < t_exit) ? t_exit  : 0.0f;

        float x = __fadd_rn(x0, __fmul_rn(te, dx));
        float y = __fadd_rn(y0, __fmul_rn(te, dy));
        int i = (int)fminf(fmaxf(rintf(__fadd_rn(x, 47.5f)), 0.0f), 95.0f);
        int j = (int)fminf(fmaxf(rintf(__fadd_rn(y, 47.5f)), 0.0f), 95.0f);
        float t = te;

        const bool okx = fabsf(dx) > EPSf;
        const bool oky = fabsf(dy) > EPSf;
        // reciprocal-mul instead of per-step IEEE div: <=2 ulp vs reference
        // (validated R2-R4: absmax stayed 0.25 vs 1.18 threshold).
        const float inv_dx = okx ? __fdiv_rn(1.0f, dx) : 0.0f;
        const float inv_dy = oky ? __fdiv_rn(1.0f, dy) : 0.0f;
        const float wscale = __fdiv_rn(DIAG, fmaxf(fabsf(dx) + fabsf(dy), EPSf));
        const float tex_m_eps = __fadd_rn(tex, -EPSf);
        // xn = (fi±0.5)-47.5 == fi + cx exactly (multiples of 0.5, |.|<144)
        const float cx = (dx > 0.0f) ? -47.0f : -48.0f;
        const float cy = (dy > 0.0f) ? -47.0f : -48.0f;
        const int   si = (dx > 0.0f) ? 1 : -1;   // dx==0 -> never selected
        const int   sj = (dy > 0.0f) ? 1 : -1;   // dy==0 -> never selected

        int n = 0;
        for (int step = 0; step < NSTEPS; ++step) {
            const bool valid = alive && (t < tex_m_eps);
            if (!__ballot(valid)) break;   // all 8 rays of the tile done
            if (valid) {
                const float txc = okx ? __fmul_rn(((float)i + cx) - x, inv_dx) : INF;
                const float tyc = oky ? __fmul_rn(((float)j + cy) - y, inv_dy) : INF;
                const float dt  = fminf(fminf(txc, tyc), __fadd_rn(tex, -t));
                const float seg = fmaxf(0.0f, __fmul_rn(dt, wscale));

                float2 e;
                e.x = __int_as_float((i * Hn + j) * (Dn * 4));  // BYTE offset
                e.y = seg;
                sE[rl][n] = e;
                ++n;

                const int i_n = i + ((txc <= tyc) ? si : 0);
                const int j_n = j + ((tyc <= txc) ? sj : 0);
                const bool inb = (i_n >= 0) && (i_n < Wn) && (j_n >= 0) && (j_n < Hn);
                x = __fadd_rn(x, __fmul_rn(dx, dt));
                y = __fadd_rn(y, __fmul_rn(dy, dt));
                t = __fadd_rn(t, dt);
                i = i_n; j = j_n;
                alive = inb;
            }
        }
        if (tracer) {
            const int n8 = (n + 7) & ~7;
            for (int p = n; p < n8; ++p) {        // zero-weight pad: w=0 * vol[0]
                float2 z; z.x = __int_as_float(0); z.y = 0.0f;
                sE[rl][p] = z;
            }
            sCnt8[rl] = n8;
        }
    }
    __syncthreads();

    // ---------------- Phase 2: gather (wave w -> ray w, lane = v) ----------------
    const int wid = tid >> 6;          // 0..7 == ray-in-tile
    const int v   = tid & 63;
    const char* __restrict__ volb = (const char*)(vol + v);

    const int cnt8 = sCnt8[wid];
    const float4* __restrict__ e4 = (const float4*)&sE[wid][0];  // 2 entries per float4

    float a0 = 0.0f, a1 = 0.0f, a2 = 0.0f, a3 = 0.0f;
    for (int n = 0; n < cnt8; n += 8) {
        const int q = n >> 1;
        const float4 p0 = e4[q + 0];   // {off0, w0, off1, w1}
        const float4 p1 = e4[q + 1];
        const float4 p2 = e4[q + 2];
        const float4 p3 = e4[q + 3];
        const float v0 = *(const float*)(volb + __float_as_int(p0.x));
        const float v1 = *(const float*)(volb + __float_as_int(p0.z));
        const float v2 = *(const float*)(volb + __float_as_int(p1.x));
        const float v3 = *(const float*)(volb + __float_as_int(p1.z));
        const float v4 = *(const float*)(volb + __float_as_int(p2.x));
        const float v5 = *(const float*)(volb + __float_as_int(p2.z));
        const float v6 = *(const float*)(volb + __float_as_int(p3.x));
        const float v7 = *(const float*)(volb + __float_as_int(p3.z));
        a0 = fmaf(p0.y, v0, a0);
        a1 = fmaf(p0.w, v1, a1);
        a2 = fmaf(p1.y, v2, a2);
        a3 = fmaf(p1.w, v3, a3);
        a0 = fmaf(p2.y, v4, a0);
        a1 = fmaf(p2.w, v5, a1);
        a2 = fmaf(p3.y, v6, a2);
        a3 = fmaf(p3.w, v7, a3);
    }
    const float acc = (a0 + a1) + (a2 + a3);

    const int ray = tile * TILE + wid;
    const int a = ray / Un;
    const int u = ray - a * Un;
    out[(u * An + a) * Vn + v] = acc;
}

extern "C" void kernel_launch(void* const* d_in, const int* in_sizes, int n_in,
                              void* d_out, int out_size, void* d_ws, size_t ws_size,
                              hipStream_t stream) {
    const float* vol = (const float*)d_in[0];
    float* out = (float*)d_out;
    hipLaunchKernelGGL(siddon_fused, dim3(NTILES), dim3(512), 0, stream, vol, out);
}